// Round 1
// 447.601 us; speedup vs baseline: 1.2012x; 1.2012x over previous
//
#include <hip/hip_runtime.h>
#include <math.h>

#define BATCH 4
#define NDET 300
#define NC 80
#define NK 17
#define HWSZ 4096
#define TOPK 300
#define NEGV -1000000000.0f
#define NW 5  // 64-bit words covering 300 bits

#define NMS_BLOCKS BATCH            // blocks 0..3 run NMS, scheduled first
#define AMAX_ROWS (BATCH * NDET * NK)

// ---------------- Fused kernel: NMS blocks (0..3) + argmax blocks (4..) ----
// NMS depends only on logits/boxes/osize; argmax streams the 334 MB heatmap
// tensor. Putting them in one launch overlaps the latency-bound 4-block NMS
// under the HBM-bound argmax stream. NMS blocks come FIRST in blockIdx so the
// scheduler starts them immediately.
__global__ __launch_bounds__(256) void fused_kernel(
    const float* __restrict__ hm,
    const float* __restrict__ logits, const float* __restrict__ boxes,
    const float* __restrict__ osize,
    float* __restrict__ kv, int* __restrict__ ki,
    float4* __restrict__ recA, float4* __restrict__ recB)
{
    int tid = threadIdx.x;

    if (blockIdx.x >= NMS_BLOCKS) {
        // ---------- argmax path: one 64-lane wave per (b,n,k) row ----------
        int wid = tid >> 6;
        int lane = tid & 63;
        int m = (blockIdx.x - NMS_BLOCKS) * 4 + wid;       // row in [0, B*N*K)
        const float4* p = (const float4*)(hm + (size_t)m * HWSZ);

        float best = -INFINITY; int bidx = 0;
#pragma unroll
        for (int c = 0; c < 16; ++c) {
            int vi = lane + 64 * c;
            float4 v = p[vi];
            int e = vi * 4;
            if (v.x > best) { best = v.x; bidx = e; }
            if (v.y > best) { best = v.y; bidx = e + 1; }
            if (v.z > best) { best = v.z; bidx = e + 2; }
            if (v.w > best) { best = v.w; bidx = e + 3; }
        }
        // wave(64) reduce, ties -> lowest index
#pragma unroll
        for (int off = 32; off > 0; off >>= 1) {
            float ov = __shfl_down(best, off, 64);
            int   oi = __shfl_down(bidx, off, 64);
            if (ov > best || (ov == best && oi < bidx)) { best = ov; bidx = oi; }
        }
        if (lane == 0) { kv[m] = best; ki[m] = bidx; }
        return;
    }

    // ---------- NMS path: one block per batch ----------
    int b = blockIdx.x;

    __shared__ float s_s[NDET];                               // score or NEG (unsorted)
    __shared__ float s_x1[NDET], s_y1[NDET], s_x2[NDET], s_y2[NDET];
    __shared__ int   s_lab[NDET];
    __shared__ int   s_order[NDET];
    __shared__ float ss[NDET];                                // sorted score/NEG
    __shared__ float ox1[NDET], oy1[NDET], ox2[NDET], oy2[NDET], oarea[NDET];
    __shared__ unsigned long long s_mask[NDET][NW];
    __shared__ unsigned long long s_valid[NW], s_rnz[NW], s_kw[NW];
    __shared__ float s_red[4];
    __shared__ float s_maxc;

    if (tid < NW) { s_valid[tid] = 0ULL; s_rnz[tid] = 0ULL; }

    // Phase 1: scores/labels/boxes
    float sx = osize[b*2+0], sy = osize[b*2+1];
    float lmax = 0.f;
    for (int n = tid; n < NDET; n += 256) {
        const float4* lg = (const float4*)(logits + ((size_t)b*NDET + n) * NC);
        float bv = -INFINITY; int bl = 0;
#pragma unroll
        for (int c = 0; c < NC / 4; ++c) {
            float4 v = lg[c];
            int e = c * 4;
            if (v.x > bv) { bv = v.x; bl = e; }
            if (v.y > bv) { bv = v.y; bl = e + 1; }
            if (v.z > bv) { bv = v.z; bl = e + 2; }
            if (v.w > bv) { bv = v.w; bl = e + 3; }
        }
        float sc = 1.0f / (1.0f + expf(-bv));
        const float4 bx = *(const float4*)(boxes + ((size_t)b*NDET + n) * 4);
        float cx = bx.x, cy = bx.y, w = bx.z, h = bx.w;
        float x1 = (cx - w*0.5f) * sx;
        float y1 = (cy - h*0.5f) * sy;
        float x2 = (cx + w*0.5f) * sx;
        float y2 = (cy + h*0.5f) * sy;
        s_s[n] = (sc > 0.01f) ? sc : NEGV;
        s_lab[n] = bl;
        s_x1[n] = x1; s_y1[n] = y1; s_x2[n] = x2; s_y2[n] = y2;
        lmax = fmaxf(lmax, fmaxf(fmaxf(fabsf(x1), fabsf(y1)), fmaxf(fabsf(x2), fabsf(y2))));
    }
#pragma unroll
    for (int off = 32; off > 0; off >>= 1)
        lmax = fmaxf(lmax, __shfl_down(lmax, off, 64));
    if ((tid & 63) == 0) s_red[tid >> 6] = lmax;
    __syncthreads();
    if (tid == 0) s_maxc = fmaxf(fmaxf(s_red[0], s_red[1]), fmaxf(s_red[2], s_red[3])) + 1.0f;
    __syncthreads();

    // Phase 2: stable descending rank sort (ties -> lower index first)
    for (int n = tid; n < NDET; n += 256) {
        float sn = s_s[n];
        int r = 0;
        for (int m = 0; m < NDET; ++m) {
            float sm = s_s[m];
            r += (sm > sn) || ((sm == sn) && (m < n));
        }
        s_order[r] = n;
    }
    __syncthreads();

    // Phase 3: sorted arrays + class-offset boxes + valid bitmask
    float maxc = s_maxc;
    for (int i = tid; i < NDET; i += 256) {
        int n = s_order[i];
        float sc = s_s[n];
        ss[i] = sc;
        float off = __fmul_rn((float)s_lab[n], maxc);
        float a1 = __fadd_rn(s_x1[n], off);
        float b1 = __fadd_rn(s_y1[n], off);
        float a2 = __fadd_rn(s_x2[n], off);
        float b2 = __fadd_rn(s_y2[n], off);
        ox1[i] = a1; oy1[i] = b1; ox2[i] = a2; oy2[i] = b2;
        oarea[i] = __fmul_rn(__fsub_rn(a2, a1), __fsub_rn(b2, b1));
        if (sc > 0.01f) atomicOr(&s_valid[i >> 6], 1ULL << (i & 63));
    }
    __syncthreads();

    // Phase 4a: parallel IoU suppression mask (only j > i bits)
    for (int task = tid; task < NDET * NW; task += 256) {
        int i = task / NW, w = task % NW;
        unsigned long long bits = 0ULL;
        int j0 = w * 64;
        int j1 = min(NDET, j0 + 64);
        int js = max(i + 1, j0);
        if (js < j1) {
            float xi1 = ox1[i], yi1 = oy1[i], xi2 = ox2[i], yi2 = oy2[i], ai = oarea[i];
            for (int j = js; j < j1; ++j) {
                float iw = fmaxf(__fsub_rn(fminf(xi2, ox2[j]), fmaxf(xi1, ox1[j])), 0.f);
                float ih = fmaxf(__fsub_rn(fminf(yi2, oy2[j]), fmaxf(yi1, oy1[j])), 0.f);
                float inter = __fmul_rn(iw, ih);
                float denom = __fadd_rn(__fsub_rn(__fadd_rn(ai, oarea[j]), inter), 1e-9f);
                float iou = __fdiv_rn(inter, denom);
                if (iou > 0.7f) bits |= 1ULL << (j - j0);
            }
        }
        s_mask[i][w] = bits;
        if (bits) atomicOr(&s_rnz[i >> 6], 1ULL << (i & 63));
    }
    __syncthreads();

    // Phase 4b: serial scan, register-resident (LDS touched only on actual suppressors)
    if (tid == 0) {
        unsigned long long sw0 = 0, sw1 = 0, sw2 = 0, sw3 = 0, sw4 = 0;
#pragma unroll
        for (int w = 0; w < NW; ++w) {
            unsigned long long vw = s_valid[w], rz = s_rnz[w], kb = 0ULL;
            int nb = (w == NW - 1) ? (NDET - 64 * (NW - 1)) : 64;
            for (int bit = 0; bit < nb; ++bit) {
                unsigned long long sww = (w == 0) ? sw0 : (w == 1) ? sw1 : (w == 2) ? sw2 : (w == 3) ? sw3 : sw4;
                if (((vw >> bit) & 1ULL) && !((sww >> bit) & 1ULL)) {
                    kb |= 1ULL << bit;
                    if ((rz >> bit) & 1ULL) {
                        int i = w * 64 + bit;
                        sw0 |= s_mask[i][0]; sw1 |= s_mask[i][1]; sw2 |= s_mask[i][2];
                        sw3 |= s_mask[i][3]; sw4 |= s_mask[i][4];
                    }
                }
            }
            s_kw[w] = kb;
        }
    }
    __syncthreads();

    // Phase 5': emit compact per-detection records for the writer kernel
    int tot = 0;
#pragma unroll
    for (int w = 0; w < NW; ++w) tot += __popcll(s_kw[w]);

    for (int it = tid; it < NDET; it += 256) {
        int w = it >> 6, bit = it & 63;
        int kb = 0;
        for (int ww = 0; ww < w; ++ww) kb += __popcll(s_kw[ww]);
        unsigned long long word = s_kw[w];
        kb += __popcll(word & ((1ULL << bit) - 1ULL));
        int vk = (int)((word >> bit) & 1ULL);
        int pos = vk ? kb : (tot + it - kb);
        int sel = s_order[it];
        recA[(size_t)b * NDET + it] =
            make_float4(s_x1[sel], s_y1[sel], s_x2[sel], s_y2[sel]);
        int packed = pos | (sel << 9) | (vk << 20);
        recB[(size_t)b * NDET + it] =
            make_float4(ss[it], (float)s_lab[sel], 0.0f, __int_as_float(packed));
    }
}

// ---------------- Writer kernel: one thread per (b, det, keypoint) ----------
// 20400 threads across 80 blocks: gathers kv/ki/koff (L2-resident, 68/136 B
// coalesced segments per det) and writes all outputs with full parallelism.
__global__ __launch_bounds__(256) void write_kernel(
    const float* __restrict__ kv, const int* __restrict__ ki,
    const float* __restrict__ koff,
    const float4* __restrict__ recA, const float4* __restrict__ recB,
    float* __restrict__ out)
{
    int t = blockIdx.x * 256 + threadIdx.x;
    if (t >= BATCH * NDET * NK) return;
    int b  = t / (NDET * NK);
    int r  = t - b * (NDET * NK);
    int it = r / NK;
    int k  = r - it * NK;

    float4 bx = recA[(size_t)b * NDET + it];
    float4 mt = recB[(size_t)b * NDET + it];
    int packed = __float_as_int(mt.w);
    int pos = packed & 511;
    int sel = (packed >> 9) & 511;
    int vk  = (packed >> 20) & 1;

    float* o_fl = out;                                   // [B,300]
    float* o_fb = out + BATCH * TOPK;                    // [B,300,4]
    float* o_fs = out + BATCH * TOPK * 5;                // [B,300]
    float* o_ak = out + BATCH * TOPK * 6;                // [B,300,17,3]
    float* o_vk = out + BATCH * TOPK * 6 + BATCH * TOPK * NK * 3;  // [B,300]

    float x1 = bx.x, y1 = bx.y, x2 = bx.z, y2 = bx.w;
    size_t ot = (size_t)b * TOPK + pos;

    if (k == 0) {
        o_fl[ot] = vk ? mt.y : -1.0f;
        o_fs[ot] = vk ? mt.x : 0.0f;
        o_vk[ot] = vk ? 1.0f : 0.0f;
        float* fb = o_fb + ot * 4;
        fb[0] = vk ? x1 : 0.f; fb[1] = vk ? y1 : 0.f;
        fb[2] = vk ? x2 : 0.f; fb[3] = vk ? y2 : 0.f;
    }

    float dx = x2 - x1, dy = y2 - y1;
    size_t kin = ((size_t)b * NDET + sel) * NK + k;
    int   idx = ki[kin];
    float val = kv[kin];
    float2 of2 = *(const float2*)(koff + kin * 2);
    float nx = fminf(fmaxf((float)(idx & 63) / 63.0f + of2.x, 0.f), 1.f);
    float ny = fminf(fmaxf((float)(idx >> 6) / 63.0f + of2.y, 0.f), 1.f);
    float ax = x1 + nx * dx;
    float ay = y1 + ny * dy;
    float* ak = o_ak + (ot * NK + k) * 3;
    ak[0] = vk ? ax : 0.f;
    ak[1] = vk ? ay : 0.f;
    ak[2] = vk ? val : 0.f;
}

extern "C" void kernel_launch(void* const* d_in, const int* in_sizes, int n_in,
                              void* d_out, int out_size, void* d_ws, size_t ws_size,
                              hipStream_t stream) {
    const float* logits = (const float*)d_in[0];   // (4,300,80)
    const float* boxes  = (const float*)d_in[1];   // (4,300,4)
    const float* hm     = (const float*)d_in[2];   // (4,300,17,64,64)
    const float* koff   = (const float*)d_in[3];   // (4,300,17,2)
    const float* osize  = (const float*)d_in[4];   // (4,2)
    float* out = (float*)d_out;

    float*  kv   = (float*)d_ws;                       // B*N*K floats   (81600 B)
    int*    ki   = (int*)(kv + AMAX_ROWS);             // B*N*K ints     (81600 B)
    float4* recA = (float4*)(ki + AMAX_ROWS);          // B*N float4    (19200 B)
    float4* recB = recA + BATCH * NDET;                // B*N float4    (19200 B)

    // 4 NMS blocks + 5100 argmax blocks (4 rows each) in ONE launch
    fused_kernel<<<NMS_BLOCKS + AMAX_ROWS / 4, 256, 0, stream>>>(
        hm, logits, boxes, osize, kv, ki, recA, recB);
    // 20400 threads: one per (b, det, keypoint)
    write_kernel<<<(BATCH * NDET * NK + 255) / 256, 256, 0, stream>>>(
        kv, ki, koff, recA, recB, out);
}